// Round 4
// baseline (277.977 us; speedup 1.0000x reference)
//
#include <hip/hip_runtime.h>
#include <math.h>

#define B_    8
#define N_    1024
#define FIN   512
#define FOUT  256
#define H_    8
#define ALPHA 0.2f
#define NEGV  -1e9f

#define XT (B_ * N_ * FIN)     // 4194304 x elements
#define WT (H_ * FOUT * FIN)   // 1048576 W elements

typedef short s16x8 __attribute__((ext_vector_type(8)));
typedef float f32x4 __attribute__((ext_vector_type(4)));

__device__ __forceinline__ unsigned short f2bf(float f) {
  unsigned int u = __float_as_uint(f);
  u = (u + 0x7FFFu + ((u >> 16) & 1u)) >> 16;   // round-to-nearest-even
  return (unsigned short)u;
}

// pack 4 fp32 -> 4 OCP e4m3 bytes (v_cvt_pk_fp8_f32; OCP format on gfx950)
__device__ __forceinline__ unsigned int pk4_fp8(float a, float b, float c,
                                                float d) {
  int u = __builtin_amdgcn_cvt_pk_fp8_f32(a, b, 0, false);   // bytes 0,1
  u = __builtin_amdgcn_cvt_pk_fp8_f32(c, d, u, true);        // bytes 2,3
  return (unsigned int)u;
}

// ---------------------------------------------------------------------------
// Kernel 0: fp32 -> bf16 conversion of x and W + zero f1/f2 (fused memset).
// ---------------------------------------------------------------------------
__global__ __launch_bounds__(256) void convert_bf16(
    const float* __restrict__ x, const float* __restrict__ W,
    unsigned short* __restrict__ xb, unsigned short* __restrict__ Wb,
    float* __restrict__ f12) {
  const int blk = blockIdx.x;
  const int CV = (XT + WT) / 1024;
  if (blk >= CV) {   // zero f1/f2: 2*H*B*N floats = 32768 float4
    const int i = (blk - CV) * 256 + threadIdx.x;
    ((float4*)f12)[i] = make_float4(0.f, 0.f, 0.f, 0.f);
    return;
  }
  const int i = (blk * 256 + threadIdx.x) * 4;
  const float* src;
  unsigned short* dst;
  int off;
  if (i < XT) { src = x; dst = xb; off = i; }
  else        { src = W; dst = Wb; off = i - XT; }
  float4 v = *(const float4*)(src + off);
  ushort4 s;
  s.x = f2bf(v.x); s.y = f2bf(v.y); s.z = f2bf(v.z); s.w = f2bf(v.w);
  *(ushort4*)(dst + off) = s;
}

// ---------------------------------------------------------------------------
// Kernel 1: projection GEMM, LDS-staged bf16 MFMA, fp8 transposed output.
// 1-D grid, b = gid&7 -> XCD k's L2 holds xb[b] (1MB) + Wb (2MB) resident.
// C-tile 128(m) x 64(o), BK=64, 256 thr. Fuses f1/f2 = h.a1/a2 (fp32 acc).
// ---------------------------------------------------------------------------
__global__ __launch_bounds__(256) void proj_mfma(
    const unsigned short* __restrict__ xb, const unsigned short* __restrict__ Wb,
    const float* __restrict__ a1, const float* __restrict__ a2,
    unsigned char* __restrict__ htq, float* __restrict__ f1,
    float* __restrict__ f2) {
  __shared__ __align__(16) unsigned short As[128 * 64];  // 16 KB
  __shared__ __align__(16) unsigned short Bs[64 * 64];   //  8 KB
  const int gid = blockIdx.x;
  const int b = gid & 7;                 // XCD-resident working set
  const int mt_ = (gid >> 3) & 7;
  const int ot_ = (gid >> 6) & 3;
  const int h = gid >> 8;
  const int hb = h * B_ + b;
  const int m0 = mt_ * 128, o0 = ot_ * 64;
  const int t = threadIdx.x, w = t >> 6, lane = t & 63;
  const int col = lane & 15, quad = lane >> 4;

  const int srow = t >> 3;
  const int sslot = t & 7;
  const int sseg = sslot ^ (srow & 7);
  const unsigned short* agp = xb + (size_t)(b * N_ + m0 + srow) * FIN + sseg * 8;
  const unsigned short* bgp = Wb + (size_t)(h * FOUT + o0 + srow) * FIN + sseg * 8;

  f32x4 acc[2][4];
  const f32x4 z4 = {0.f, 0.f, 0.f, 0.f};
#pragma unroll
  for (int mt = 0; mt < 2; ++mt)
#pragma unroll
    for (int ot = 0; ot < 4; ++ot) acc[mt][ot] = z4;

  s16x8 pa[4], pb[2];
#pragma unroll
  for (int i2 = 0; i2 < 4; ++i2) pa[i2] = *(const s16x8*)(agp + (size_t)i2 * 32 * FIN);
#pragma unroll
  for (int i2 = 0; i2 < 2; ++i2) pb[i2] = *(const s16x8*)(bgp + (size_t)i2 * 32 * FIN);

  for (int it = 0; it < FIN / 64; ++it) {
    __syncthreads();
#pragma unroll
    for (int i2 = 0; i2 < 4; ++i2)
      *(s16x8*)&As[(i2 * 32 + srow) * 64 + sslot * 8] = pa[i2];
#pragma unroll
    for (int i2 = 0; i2 < 2; ++i2)
      *(s16x8*)&Bs[(i2 * 32 + srow) * 64 + sslot * 8] = pb[i2];
    __syncthreads();
    if (it < FIN / 64 - 1) {
      const int k0 = (it + 1) * 64;
#pragma unroll
      for (int i2 = 0; i2 < 4; ++i2)
        pa[i2] = *(const s16x8*)(agp + (size_t)i2 * 32 * FIN + k0);
#pragma unroll
      for (int i2 = 0; i2 < 2; ++i2)
        pb[i2] = *(const s16x8*)(bgp + (size_t)i2 * 32 * FIN + k0);
    }
#pragma unroll
    for (int kb = 0; kb < 2; ++kb) {
      s16x8 af[2], bf[4];
#pragma unroll
      for (int mt = 0; mt < 2; ++mt) {
        const int row = w * 32 + mt * 16 + col;
        af[mt] = *(const s16x8*)&As[row * 64 + ((kb * 4 + quad) ^ (row & 7)) * 8];
      }
#pragma unroll
      for (int ot = 0; ot < 4; ++ot) {
        const int row = ot * 16 + col;
        bf[ot] = *(const s16x8*)&Bs[row * 64 + ((kb * 4 + quad) ^ (row & 7)) * 8];
      }
#pragma unroll
      for (int mt = 0; mt < 2; ++mt)
#pragma unroll
        for (int ot = 0; ot < 4; ++ot)
          acc[mt][ot] = __builtin_amdgcn_mfma_f32_16x16x32_bf16(af[mt], bf[ot],
                                                                acc[mt][ot], 0, 0, 0);
    }
  }

  // epilogue: fp8 transposed store + fused f1/f2 partials
  float pf1[2][4] = {{0.f}}, pf2[2][4] = {{0.f}};
#pragma unroll
  for (int mt = 0; mt < 2; ++mt) {
#pragma unroll
    for (int ot = 0; ot < 4; ++ot) {
      const int o = o0 + ot * 16 + col;
      const float va1 = a1[h * FOUT + o], va2 = a2[h * FOUT + o];
      const int m = m0 + w * 32 + mt * 16 + quad * 4;
      const unsigned int q =
          pk4_fp8(acc[mt][ot][0], acc[mt][ot][1], acc[mt][ot][2], acc[mt][ot][3]);
      *(unsigned int*)(htq + (size_t)(hb * FOUT + o) * N_ + m) = q;
#pragma unroll
      for (int r = 0; r < 4; ++r) {
        pf1[mt][r] += acc[mt][ot][r] * va1;
        pf2[mt][r] += acc[mt][ot][r] * va2;
      }
    }
  }
#pragma unroll
  for (int off = 1; off <= 8; off <<= 1)
#pragma unroll
    for (int mt = 0; mt < 2; ++mt)
#pragma unroll
      for (int r = 0; r < 4; ++r) {
        pf1[mt][r] += __shfl_xor(pf1[mt][r], off);
        pf2[mt][r] += __shfl_xor(pf2[mt][r], off);
      }
  if (col == 0) {
#pragma unroll
    for (int mt = 0; mt < 2; ++mt)
#pragma unroll
      for (int r = 0; r < 4; ++r) {
        const int n = m0 + w * 32 + mt * 16 + quad * 4 + r;
        atomicAdd(&f1[hb * N_ + n], pf1[mt][r]);
        atomicAdd(&f2[hb * N_ + n], pf2[mt][r]);
      }
  }
}

// ---------------------------------------------------------------------------
// Kernel 2: fused attention, 2 heads per block, fp8 weights + fp8 PV MFMA.
// Grid 1024 = (b, 4 head-groups, 32 i-tiles); ~38KB LDS -> 4 blocks/CU.
// ---------------------------------------------------------------------------
__global__ __launch_bounds__(512, 8) void attn_mfma(
    const unsigned char* __restrict__ htq, const float* __restrict__ f1,
    const float* __restrict__ f2, const int* __restrict__ adj,
    float* __restrict__ p0, float* __restrict__ p1, float* __restrict__ p2,
    float* __restrict__ p3) {
  __shared__ __align__(16) unsigned char wlds[32][1040];  // fp8 weights, 33KB
  __shared__ unsigned int adjb[32][32];
  __shared__ float s_inv[32];

  const int id = blockIdx.x;
  const int b = id & 7;                 // XCD-keyed: htq[.][b] = 2MB in L2
  const int g0 = (id >> 3) & 3;        // head group: heads {2g0, 2g0+1}
  const int i0 = (id >> 5) * 32;
  const int tid = threadIdx.x, w = tid >> 6, lane = tid & 63;
  const int col = lane & 15, quad = lane >> 4;

  // adjacency bitmask: 32 rows x 1024 bits, built once, reused for 2 heads
  for (int wi = tid; wi < 32 * 32; wi += 512) {
    const int row = wi >> 5, word = wi & 31;
    const int* ap = adj + (size_t)(b * N_ + i0 + row) * N_ + word * 32;
    unsigned int bits = 0;
#pragma unroll
    for (int k = 0; k < 32; k += 4) {
      int4 v = *(const int4*)(ap + k);
      bits |= (v.x ? 1u : 0u) << k;
      bits |= (v.y ? 1u : 0u) << (k + 1);
      bits |= (v.z ? 1u : 0u) << (k + 2);
      bits |= (v.w ? 1u : 0u) << (k + 3);
    }
    adjb[row][word] = bits;
  }
  __syncthreads();

  float hsum[2][2][4];
#pragma unroll
  for (int g = 0; g < 2; ++g)
#pragma unroll
    for (int t = 0; t < 2; ++t)
#pragma unroll
      for (int r = 0; r < 4; ++r) hsum[g][t][r] = 0.f;

  for (int hh = 0; hh < 2; ++hh) {
    const int h = g0 * 2 + hh;
    const int hb = h * B_ + b;
    const float* f1r = f1 + (size_t)hb * N_ + i0;
    // cache f2 row: lane owns j = c*256 + 4*lane .. +3
    float4 f2c[4];
#pragma unroll
    for (int c = 0; c < 4; ++c)
      f2c[c] = ((const float4*)(f2 + (size_t)hb * N_))[c * 64 + lane];

    // ---- scores: wave w owns rows 4w..4w+3; weights packed fp8 ----
#pragma unroll
    for (int rr = 0; rr < 4; ++rr) {
      const int i = w * 4 + rr;
      const float f1i = f1r[i];
      unsigned int nib[4];
      float m = -3.0e38f;
#pragma unroll
      for (int c = 0; c < 4; ++c) {
        const int j0 = c * 256 + (lane << 2);
        nib[c] = (adjb[i][j0 >> 5] >> (j0 & 31)) & 0xFu;
#pragma unroll
        for (int k = 0; k < 4; ++k) {
          float e = f1i + ((const float*)&f2c[c])[k];
          e = fmaxf(e, ALPHA * e);
          e = ((nib[c] >> k) & 1u) ? e : NEGV;
          m = fmaxf(m, e);
        }
      }
#pragma unroll
      for (int off = 32; off; off >>= 1) m = fmaxf(m, __shfl_xor(m, off));
      float l = 0.f;
#pragma unroll
      for (int c = 0; c < 4; ++c) {
        float ex[4];
#pragma unroll
        for (int k = 0; k < 4; ++k) {
          float e = f1i + ((const float*)&f2c[c])[k];
          e = fmaxf(e, ALPHA * e);
          e = ((nib[c] >> k) & 1u) ? e : NEGV;
          ex[k] = __expf(e - m);
          l += ex[k];
        }
        *(unsigned int*)&wlds[i][c * 256 + (lane << 2)] =
            pk4_fp8(ex[0], ex[1], ex[2], ex[3]);
      }
#pragma unroll
      for (int off = 32; off; off >>= 1) l += __shfl_xor(l, off);
      if (lane == 0) s_inv[i] = 1.0f / l;
    }
    __syncthreads();

    // ---- PV: fp8 MFMA, D[i][o] = sum_j w[i][j] * h[j][o] ----
    f32x4 acc[2][2];
    const f32x4 z4 = {0.f, 0.f, 0.f, 0.f};
#pragma unroll
    for (int g = 0; g < 2; ++g)
#pragma unroll
      for (int t = 0; t < 2; ++t) acc[g][t] = z4;

    const unsigned char* bp =
        htq + (size_t)(hb * FOUT + w * 32 + col) * N_ + quad * 8;
    const unsigned char* a0p = &wlds[col][quad * 8];
    const unsigned char* a1p = &wlds[16 + col][quad * 8];
#pragma unroll 4
    for (int kk = 0; kk < 32; ++kk) {
      const long af0 = *(const long*)(a0p + kk * 32);
      const long af1 = *(const long*)(a1p + kk * 32);
#pragma unroll
      for (int t = 0; t < 2; ++t) {
        const long bf = *(const long*)(bp + (size_t)t * 16 * N_ + kk * 32);
        acc[0][t] = __builtin_amdgcn_mfma_f32_16x16x32_fp8_fp8(af0, bf,
                                                               acc[0][t], 0, 0, 0);
        acc[1][t] = __builtin_amdgcn_mfma_f32_16x16x32_fp8_fp8(af1, bf,
                                                               acc[1][t], 0, 0, 0);
      }
    }

    // normalize, ELU, head-sum
#pragma unroll
    for (int g = 0; g < 2; ++g)
#pragma unroll
      for (int t = 0; t < 2; ++t)
#pragma unroll
        for (int r = 0; r < 4; ++r) {
          const float oh = acc[g][t][r] * s_inv[g * 16 + quad * 4 + r];
          hsum[g][t][r] += oh > 0.f ? oh : __expf(oh) - 1.f;
        }
    __syncthreads();   // wlds/s_inv reused next head
  }

  // ---- write head-group partial ----
  float* pdst = (g0 == 0) ? p0 : (g0 == 1) ? p1 : (g0 == 2) ? p2 : p3;
#pragma unroll
  for (int g = 0; g < 2; ++g)
#pragma unroll
    for (int t = 0; t < 2; ++t)
#pragma unroll
      for (int r = 0; r < 4; ++r) {
        const int row = g * 16 + quad * 4 + r;
        pdst[(size_t)(b * N_ + i0 + row) * FOUT + w * 32 + t * 16 + col] =
            hsum[g][t][r];
      }
}

// ---------------------------------------------------------------------------
// Kernel 3: sum 4 head-group partials + log_softmax over o. Wave per row.
// ---------------------------------------------------------------------------
__global__ __launch_bounds__(256) void logsm(
    const float* __restrict__ p0, const float* __restrict__ p1,
    const float* __restrict__ p2, const float* __restrict__ p3,
    float* __restrict__ out) {
  const int row = blockIdx.x * 4 + (threadIdx.x >> 6);
  const int lane = threadIdx.x & 63;
  const size_t base = (size_t)row * FOUT;
  float v[4];
  float m = -3.0e38f;
#pragma unroll
  for (int c = 0; c < 4; ++c) {
    const size_t idx = base + c * 64 + lane;
    v[c] = p0[idx] + p1[idx] + p2[idx] + p3[idx];
    m = fmaxf(m, v[c]);
  }
#pragma unroll
  for (int off = 32; off; off >>= 1) m = fmaxf(m, __shfl_xor(m, off));
  float s = 0.f;
#pragma unroll
  for (int c = 0; c < 4; ++c) s += __expf(v[c] - m);
#pragma unroll
  for (int off = 32; off; off >>= 1) s += __shfl_xor(s, off);
  const float lg = m + logf(s);
#pragma unroll
  for (int c = 0; c < 4; ++c)
    out[base + c * 64 + lane] = v[c] - lg;
}

// ---------------------------------------------------------------------------
extern "C" void kernel_launch(void* const* d_in, const int* in_sizes, int n_in,
                              void* d_out, int out_size, void* d_ws,
                              size_t ws_size, hipStream_t stream) {
  const float* x   = (const float*)d_in[0];
  const int*   adj = (const int*)d_in[1];
  const float* W   = (const float*)d_in[2];
  const float* a1  = (const float*)d_in[3];
  const float* a2  = (const float*)d_in[4];
  float* out = (float*)d_out;

  unsigned char* htq = (unsigned char*)d_ws;                          // 16 MB fp8 h^T
  unsigned short* xb = (unsigned short*)(htq + (size_t)H_ * B_ * FOUT * N_); // 8 MB
  unsigned short* Wb = xb + (size_t)XT;                               // 2 MB
  float* f1 = (float*)(Wb + (size_t)WT);                              // 256 KB
  float* f2 = f1 + (size_t)H_ * B_ * N_;                              // 256 KB
  float* part2 = f2 + (size_t)H_ * B_ * N_;                           // 8 MB
  float* part3 = part2 + (size_t)B_ * N_ * FOUT;                      // 8 MB
  float* part1 = (float*)xb;   // xb dead after proj_mfma (8 MB reuse)

  convert_bf16<<<(XT + WT) / 1024 + 128, 256, 0, stream>>>(x, W, xb, Wb, f1);

  proj_mfma<<<2048, 256, 0, stream>>>(xb, Wb, a1, a2, htq, f1, f2);

  attn_mfma<<<1024, 512, 0, stream>>>(htq, f1, f2, adj, out, part1, part2, part3);

  logsm<<<(B_ * N_) / 4, 256, 0, stream>>>(out, part1, part2, part3, out);
}

// Round 5
// 276.644 us; speedup vs baseline: 1.0048x; 1.0048x over previous
//
#include <hip/hip_runtime.h>
#include <math.h>

#define B_    8
#define N_    1024
#define FIN   512
#define FOUT  256
#define H_    8
#define ALPHA 0.2f

#define XT (B_ * N_ * FIN)     // 4194304 x elements
#define WT (H_ * FOUT * FIN)   // 1048576 W elements

typedef short s16x8 __attribute__((ext_vector_type(8)));
typedef float f32x4 __attribute__((ext_vector_type(4)));

__device__ __forceinline__ unsigned short f2bf(float f) {
  unsigned int u = __float_as_uint(f);
  u = (u + 0x7FFFu + ((u >> 16) & 1u)) >> 16;   // round-to-nearest-even
  return (unsigned short)u;
}

// pack 4 fp32 -> 4 OCP e4m3 bytes (v_cvt_pk_fp8_f32; OCP format on gfx950)
__device__ __forceinline__ unsigned int pk4_fp8(float a, float b, float c,
                                                float d) {
  int u = __builtin_amdgcn_cvt_pk_fp8_f32(a, b, 0, false);   // bytes 0,1
  u = __builtin_amdgcn_cvt_pk_fp8_f32(c, d, u, true);        // bytes 2,3
  return (unsigned int)u;
}

// ---------------------------------------------------------------------------
// Kernel 0: fp32 -> bf16 conversion of x and W + zero f1/f2 (fused memset).
// ---------------------------------------------------------------------------
__global__ __launch_bounds__(256) void convert_bf16(
    const float* __restrict__ x, const float* __restrict__ W,
    unsigned short* __restrict__ xb, unsigned short* __restrict__ Wb,
    float* __restrict__ f12) {
  const int blk = blockIdx.x;
  const int CV = (XT + WT) / 1024;
  if (blk >= CV) {   // zero f1/f2: 2*H*B*N floats = 32768 float4
    const int i = (blk - CV) * 256 + threadIdx.x;
    ((float4*)f12)[i] = make_float4(0.f, 0.f, 0.f, 0.f);
    return;
  }
  const int i = (blk * 256 + threadIdx.x) * 4;
  const float* src;
  unsigned short* dst;
  int off;
  if (i < XT) { src = x; dst = xb; off = i; }
  else        { src = W; dst = Wb; off = i - XT; }
  float4 v = *(const float4*)(src + off);
  ushort4 s;
  s.x = f2bf(v.x); s.y = f2bf(v.y); s.z = f2bf(v.z); s.w = f2bf(v.w);
  *(ushort4*)(dst + off) = s;
}

// ---------------------------------------------------------------------------
// Kernel 1: projection GEMM, LDS-staged bf16 MFMA, fp8 transposed output.
// 1-D grid, b = gid&7 -> XCD k's L2 holds xb[b] (1MB) + Wb (2MB) resident.
// C-tile 128(m) x 64(o), BK=64, 256 thr. Fuses f1/f2 = h.a1/a2 (fp32 acc).
// ---------------------------------------------------------------------------
__global__ __launch_bounds__(256) void proj_mfma(
    const unsigned short* __restrict__ xb, const unsigned short* __restrict__ Wb,
    const float* __restrict__ a1, const float* __restrict__ a2,
    unsigned char* __restrict__ htq, float* __restrict__ f1,
    float* __restrict__ f2) {
  __shared__ __align__(16) unsigned short As[128 * 64];  // 16 KB
  __shared__ __align__(16) unsigned short Bs[64 * 64];   //  8 KB
  const int gid = blockIdx.x;
  const int b = gid & 7;                 // XCD-resident working set
  const int mt_ = (gid >> 3) & 7;
  const int ot_ = (gid >> 6) & 3;
  const int h = gid >> 8;
  const int hb = h * B_ + b;
  const int m0 = mt_ * 128, o0 = ot_ * 64;
  const int t = threadIdx.x, w = t >> 6, lane = t & 63;
  const int col = lane & 15, quad = lane >> 4;

  const int srow = t >> 3;
  const int sslot = t & 7;
  const int sseg = sslot ^ (srow & 7);
  const unsigned short* agp = xb + (size_t)(b * N_ + m0 + srow) * FIN + sseg * 8;
  const unsigned short* bgp = Wb + (size_t)(h * FOUT + o0 + srow) * FIN + sseg * 8;

  f32x4 acc[2][4];
  const f32x4 z4 = {0.f, 0.f, 0.f, 0.f};
#pragma unroll
  for (int mt = 0; mt < 2; ++mt)
#pragma unroll
    for (int ot = 0; ot < 4; ++ot) acc[mt][ot] = z4;

  s16x8 pa[4], pb[2];
#pragma unroll
  for (int i2 = 0; i2 < 4; ++i2) pa[i2] = *(const s16x8*)(agp + (size_t)i2 * 32 * FIN);
#pragma unroll
  for (int i2 = 0; i2 < 2; ++i2) pb[i2] = *(const s16x8*)(bgp + (size_t)i2 * 32 * FIN);

  for (int it = 0; it < FIN / 64; ++it) {
    __syncthreads();
#pragma unroll
    for (int i2 = 0; i2 < 4; ++i2)
      *(s16x8*)&As[(i2 * 32 + srow) * 64 + sslot * 8] = pa[i2];
#pragma unroll
    for (int i2 = 0; i2 < 2; ++i2)
      *(s16x8*)&Bs[(i2 * 32 + srow) * 64 + sslot * 8] = pb[i2];
    __syncthreads();
    if (it < FIN / 64 - 1) {
      const int k0 = (it + 1) * 64;
#pragma unroll
      for (int i2 = 0; i2 < 4; ++i2)
        pa[i2] = *(const s16x8*)(agp + (size_t)i2 * 32 * FIN + k0);
#pragma unroll
      for (int i2 = 0; i2 < 2; ++i2)
        pb[i2] = *(const s16x8*)(bgp + (size_t)i2 * 32 * FIN + k0);
    }
#pragma unroll
    for (int kb = 0; kb < 2; ++kb) {
      s16x8 af[2], bf[4];
#pragma unroll
      for (int mt = 0; mt < 2; ++mt) {
        const int row = w * 32 + mt * 16 + col;
        af[mt] = *(const s16x8*)&As[row * 64 + ((kb * 4 + quad) ^ (row & 7)) * 8];
      }
#pragma unroll
      for (int ot = 0; ot < 4; ++ot) {
        const int row = ot * 16 + col;
        bf[ot] = *(const s16x8*)&Bs[row * 64 + ((kb * 4 + quad) ^ (row & 7)) * 8];
      }
#pragma unroll
      for (int mt = 0; mt < 2; ++mt)
#pragma unroll
        for (int ot = 0; ot < 4; ++ot)
          acc[mt][ot] = __builtin_amdgcn_mfma_f32_16x16x32_bf16(af[mt], bf[ot],
                                                                acc[mt][ot], 0, 0, 0);
    }
  }

  // epilogue: fp8 transposed store + fused f1/f2 partials
  float pf1[2][4] = {{0.f}}, pf2[2][4] = {{0.f}};
#pragma unroll
  for (int mt = 0; mt < 2; ++mt) {
#pragma unroll
    for (int ot = 0; ot < 4; ++ot) {
      const int o = o0 + ot * 16 + col;
      const float va1 = a1[h * FOUT + o], va2 = a2[h * FOUT + o];
      const int m = m0 + w * 32 + mt * 16 + quad * 4;
      const unsigned int q =
          pk4_fp8(acc[mt][ot][0], acc[mt][ot][1], acc[mt][ot][2], acc[mt][ot][3]);
      *(unsigned int*)(htq + (size_t)(hb * FOUT + o) * N_ + m) = q;
#pragma unroll
      for (int r = 0; r < 4; ++r) {
        pf1[mt][r] += acc[mt][ot][r] * va1;
        pf2[mt][r] += acc[mt][ot][r] * va2;
      }
    }
  }
#pragma unroll
  for (int off = 1; off <= 8; off <<= 1)
#pragma unroll
    for (int mt = 0; mt < 2; ++mt)
#pragma unroll
      for (int r = 0; r < 4; ++r) {
        pf1[mt][r] += __shfl_xor(pf1[mt][r], off);
        pf2[mt][r] += __shfl_xor(pf2[mt][r], off);
      }
  if (col == 0) {
#pragma unroll
    for (int mt = 0; mt < 2; ++mt)
#pragma unroll
      for (int r = 0; r < 4; ++r) {
        const int n = m0 + w * 32 + mt * 16 + quad * 4 + r;
        atomicAdd(&f1[hb * N_ + n], pf1[mt][r]);
        atomicAdd(&f2[hb * N_ + n], pf2[mt][r]);
      }
  }
}

// ---------------------------------------------------------------------------
// Kernel 2: fused attention, 2 heads per block, fp8 weights + fp8 PV MFMA.
// Reduction-free score pass: per-row max BOUND m^ = leaky(f1[i] + max_j f2[j])
// (monotone leaky => exp(e - m^) <= 1); softmax denominator comes from an
// extra MFMA ones-column (B = fp8 1.0 splat), landing in C-layout exactly
// where normalization needs it. No shuffle reductions, no NEGV, one pass.
// Grid 1024 = (b, 4 head-groups, 32 i-tiles); ~38KB LDS -> 4 blocks/CU.
// ---------------------------------------------------------------------------
__global__ __launch_bounds__(512, 8) void attn_mfma(
    const unsigned char* __restrict__ htq, const float* __restrict__ f1,
    const float* __restrict__ f2, const int* __restrict__ adj,
    float* __restrict__ p0, float* __restrict__ p1, float* __restrict__ p2,
    float* __restrict__ p3) {
  __shared__ __align__(16) unsigned char wlds[32][1040];  // fp8 weights, 33KB
  __shared__ unsigned int adjb[32][32];
  __shared__ float mred[2][8];

  const int id = blockIdx.x;
  const int b = id & 7;                 // XCD-keyed: htq[.][b] slices in L2
  const int g0 = (id >> 3) & 3;        // head group: heads {2g0, 2g0+1}
  const int i0 = (id >> 5) * 32;
  const int tid = threadIdx.x, w = tid >> 6, lane = tid & 63;
  const int col = lane & 15, quad = lane >> 4;

  // adjacency bitmask: 32 rows x 1024 bits, built once, reused for 2 heads
  for (int wi = tid; wi < 32 * 32; wi += 512) {
    const int row = wi >> 5, word = wi & 31;
    const int* ap = adj + (size_t)(b * N_ + i0 + row) * N_ + word * 32;
    unsigned int bits = 0;
#pragma unroll
    for (int k = 0; k < 32; k += 4) {
      int4 v = *(const int4*)(ap + k);
      bits |= (v.x ? 1u : 0u) << k;
      bits |= (v.y ? 1u : 0u) << (k + 1);
      bits |= (v.z ? 1u : 0u) << (k + 2);
      bits |= (v.w ? 1u : 0u) << (k + 3);
    }
    adjb[row][word] = bits;
  }

  // M2[s] = max_j f2[(2g0+s)*B+b][j]  (merged into the adjb barrier)
  float m2p[2];
#pragma unroll
  for (int s = 0; s < 2; ++s) {
    const float* fp = f2 + (size_t)((g0 * 2 + s) * B_ + b) * N_;
    m2p[s] = fmaxf(fp[tid], fp[tid + 512]);
#pragma unroll
    for (int off = 32; off; off >>= 1)
      m2p[s] = fmaxf(m2p[s], __shfl_xor(m2p[s], off));
  }
  if (lane == 0) { mred[0][w] = m2p[0]; mred[1][w] = m2p[1]; }
  __syncthreads();
  float M2[2];
#pragma unroll
  for (int s = 0; s < 2; ++s) {
    float m = mred[s][0];
#pragma unroll
    for (int k = 1; k < 8; ++k) m = fmaxf(m, mred[s][k]);
    M2[s] = m;
  }

  float hsum[2][2][4];
#pragma unroll
  for (int g = 0; g < 2; ++g)
#pragma unroll
    for (int t = 0; t < 2; ++t)
#pragma unroll
      for (int r = 0; r < 4; ++r) hsum[g][t][r] = 0.f;

  for (int hh = 0; hh < 2; ++hh) {
    const int h = g0 * 2 + hh;
    const int hb = h * B_ + b;
    const float* f1r = f1 + (size_t)hb * N_ + i0;
    // cache f2 row: lane owns j = c*256 + 4*lane .. +3
    float4 f2c[4];
#pragma unroll
    for (int c = 0; c < 4; ++c)
      f2c[c] = ((const float4*)(f2 + (size_t)hb * N_))[c * 64 + lane];

    // ---- scores: one pass, no reductions; wave w owns rows 4w..4w+3 ----
#pragma unroll
    for (int rr = 0; rr < 4; ++rr) {
      const int i = w * 4 + rr;
      const float f1i = f1r[i];
      const float tb = f1i + M2[hh];
      const float mhat = fmaxf(tb, ALPHA * tb);   // >= leaky(f1i+f2j) for all j
#pragma unroll
      for (int c = 0; c < 4; ++c) {
        const int j0 = c * 256 + (lane << 2);
        const unsigned int nib = (adjb[i][j0 >> 5] >> (j0 & 31)) & 0xFu;
        float ex[4];
#pragma unroll
        for (int k = 0; k < 4; ++k) {
          const float t = f1i + ((const float*)&f2c[c])[k];
          const float l = fmaxf(t, ALPHA * t);
          const float p = __expf(l - mhat);       // <= 1
          ex[k] = ((nib >> k) & 1u) ? p : 0.f;
        }
        *(unsigned int*)&wlds[i][c * 256 + (lane << 2)] =
            pk4_fp8(ex[0], ex[1], ex[2], ex[3]);
      }
    }
    __syncthreads();

    // ---- PV: fp8 MFMA; ones-column MFMA yields the softmax denominators ----
    f32x4 acc[2][2], accs[2];
    const f32x4 z4 = {0.f, 0.f, 0.f, 0.f};
#pragma unroll
    for (int g = 0; g < 2; ++g) {
      accs[g] = z4;
#pragma unroll
      for (int t = 0; t < 2; ++t) acc[g][t] = z4;
    }
    const long ones = 0x3838383838383838L;   // 8x fp8 e4m3 1.0

    const unsigned char* bp =
        htq + (size_t)(hb * FOUT + w * 32 + col) * N_ + quad * 8;
    const unsigned char* a0p = &wlds[col][quad * 8];
    const unsigned char* a1p = &wlds[16 + col][quad * 8];
#pragma unroll 4
    for (int kk = 0; kk < 32; ++kk) {
      const long af0 = *(const long*)(a0p + kk * 32);
      const long af1 = *(const long*)(a1p + kk * 32);
      accs[0] = __builtin_amdgcn_mfma_f32_16x16x32_fp8_fp8(af0, ones, accs[0], 0, 0, 0);
      accs[1] = __builtin_amdgcn_mfma_f32_16x16x32_fp8_fp8(af1, ones, accs[1], 0, 0, 0);
#pragma unroll
      for (int t = 0; t < 2; ++t) {
        const long bf = *(const long*)(bp + (size_t)t * 16 * N_ + kk * 32);
        acc[0][t] = __builtin_amdgcn_mfma_f32_16x16x32_fp8_fp8(af0, bf,
                                                               acc[0][t], 0, 0, 0);
        acc[1][t] = __builtin_amdgcn_mfma_f32_16x16x32_fp8_fp8(af1, bf,
                                                               acc[1][t], 0, 0, 0);
      }
    }

    // normalize (denominator = accs, same quantized weights as numerator),
    // ELU, head-sum
#pragma unroll
    for (int g = 0; g < 2; ++g)
#pragma unroll
      for (int r = 0; r < 4; ++r) {
        const float inv = 1.0f / accs[g][r];
#pragma unroll
        for (int t = 0; t < 2; ++t) {
          const float oh = acc[g][t][r] * inv;
          hsum[g][t][r] += oh > 0.f ? oh : __expf(oh) - 1.f;
        }
      }
    __syncthreads();   // wlds reused next head
  }

  // ---- write head-group partial ----
  float* pdst = (g0 == 0) ? p0 : (g0 == 1) ? p1 : (g0 == 2) ? p2 : p3;
#pragma unroll
  for (int g = 0; g < 2; ++g)
#pragma unroll
    for (int t = 0; t < 2; ++t)
#pragma unroll
      for (int r = 0; r < 4; ++r) {
        const int row = g * 16 + quad * 4 + r;
        pdst[(size_t)(b * N_ + i0 + row) * FOUT + w * 32 + t * 16 + col] =
            hsum[g][t][r];
      }
}

// ---------------------------------------------------------------------------
// Kernel 3: sum 4 head-group partials + log_softmax over o. Wave per row.
// ---------------------------------------------------------------------------
__global__ __launch_bounds__(256) void logsm(
    const float* __restrict__ p0, const float* __restrict__ p1,
    const float* __restrict__ p2, const float* __restrict__ p3,
    float* __restrict__ out) {
  const int row = blockIdx.x * 4 + (threadIdx.x >> 6);
  const int lane = threadIdx.x & 63;
  const size_t base = (size_t)row * FOUT;
  float v[4];
  float m = -3.0e38f;
#pragma unroll
  for (int c = 0; c < 4; ++c) {
    const size_t idx = base + c * 64 + lane;
    v[c] = p0[idx] + p1[idx] + p2[idx] + p3[idx];
    m = fmaxf(m, v[c]);
  }
#pragma unroll
  for (int off = 32; off; off >>= 1) m = fmaxf(m, __shfl_xor(m, off));
  float s = 0.f;
#pragma unroll
  for (int c = 0; c < 4; ++c) s += __expf(v[c] - m);
#pragma unroll
  for (int off = 32; off; off >>= 1) s += __shfl_xor(s, off);
  const float lg = m + logf(s);
#pragma unroll
  for (int c = 0; c < 4; ++c)
    out[base + c * 64 + lane] = v[c] - lg;
}

// ---------------------------------------------------------------------------
extern "C" void kernel_launch(void* const* d_in, const int* in_sizes, int n_in,
                              void* d_out, int out_size, void* d_ws,
                              size_t ws_size, hipStream_t stream) {
  const float* x   = (const float*)d_in[0];
  const int*   adj = (const int*)d_in[1];
  const float* W   = (const float*)d_in[2];
  const float* a1  = (const float*)d_in[3];
  const float* a2  = (const float*)d_in[4];
  float* out = (float*)d_out;

  unsigned char* htq = (unsigned char*)d_ws;                          // 16 MB fp8 h^T
  unsigned short* xb = (unsigned short*)(htq + (size_t)H_ * B_ * FOUT * N_); // 8 MB
  unsigned short* Wb = xb + (size_t)XT;                               // 2 MB
  float* f1 = (float*)(Wb + (size_t)WT);                              // 256 KB
  float* f2 = f1 + (size_t)H_ * B_ * N_;                              // 256 KB
  float* part2 = f2 + (size_t)H_ * B_ * N_;                           // 8 MB
  float* part3 = part2 + (size_t)B_ * N_ * FOUT;                      // 8 MB
  float* part1 = (float*)xb;   // xb dead after proj_mfma (8 MB reuse)

  convert_bf16<<<(XT + WT) / 1024 + 128, 256, 0, stream>>>(x, W, xb, Wb, f1);

  proj_mfma<<<2048, 256, 0, stream>>>(xb, Wb, a1, a2, htq, f1, f2);

  attn_mfma<<<1024, 512, 0, stream>>>(htq, f1, f2, adj, out, part1, part2, part3);

  logsm<<<(B_ * N_) / 4, 256, 0, stream>>>(out, part1, part2, part3, out);
}

// Round 6
// 267.898 us; speedup vs baseline: 1.0376x; 1.0326x over previous
//
#include <hip/hip_runtime.h>
#include <math.h>

#define B_    8
#define N_    1024
#define FIN   512
#define FOUT  256
#define H_    8
#define ALPHA 0.2f

#define XT (B_ * N_ * FIN)     // 4194304 x elements
#define WT (H_ * FOUT * FIN)   // 1048576 W elements

#define WROW 1044              // wlds row stride in bytes (odd dword count:
                               // 261 -> banks (5*col+2*quad) mod 32, ~2-way)

typedef short s16x8 __attribute__((ext_vector_type(8)));
typedef float f32x4 __attribute__((ext_vector_type(4)));

__device__ __forceinline__ unsigned short f2bf(float f) {
  unsigned int u = __float_as_uint(f);
  u = (u + 0x7FFFu + ((u >> 16) & 1u)) >> 16;   // round-to-nearest-even
  return (unsigned short)u;
}

// pack 4 fp32 -> 4 OCP e4m3 bytes (v_cvt_pk_fp8_f32; OCP format on gfx950)
__device__ __forceinline__ unsigned int pk4_fp8(float a, float b, float c,
                                                float d) {
  int u = __builtin_amdgcn_cvt_pk_fp8_f32(a, b, 0, false);   // bytes 0,1
  u = __builtin_amdgcn_cvt_pk_fp8_f32(c, d, u, true);        // bytes 2,3
  return (unsigned int)u;
}

// ---------------------------------------------------------------------------
// Kernel 0: fp32 -> bf16 conversion of x and W + zero f1/f2 (fused memset).
// ---------------------------------------------------------------------------
__global__ __launch_bounds__(256) void convert_bf16(
    const float* __restrict__ x, const float* __restrict__ W,
    unsigned short* __restrict__ xb, unsigned short* __restrict__ Wb,
    float* __restrict__ f12) {
  const int blk = blockIdx.x;
  const int CV = (XT + WT) / 1024;
  if (blk >= CV) {   // zero f1/f2: 2*H*B*N floats = 32768 float4
    const int i = (blk - CV) * 256 + threadIdx.x;
    ((float4*)f12)[i] = make_float4(0.f, 0.f, 0.f, 0.f);
    return;
  }
  const int i = (blk * 256 + threadIdx.x) * 4;
  const float* src;
  unsigned short* dst;
  int off;
  if (i < XT) { src = x; dst = xb; off = i; }
  else        { src = W; dst = Wb; off = i - XT; }
  float4 v = *(const float4*)(src + off);
  ushort4 s;
  s.x = f2bf(v.x); s.y = f2bf(v.y); s.z = f2bf(v.z); s.w = f2bf(v.w);
  *(ushort4*)(dst + off) = s;
}

// ---------------------------------------------------------------------------
// Kernel 1: projection GEMM, LDS-staged bf16 MFMA, fp8 transposed output.
// 1-D grid, b = gid&7 -> XCD k's L2 holds xb[b] (1MB) + Wb (2MB) resident.
// C-tile 128(m) x 64(o), BK=64, 256 thr. Fuses f1/f2 = h.a1/a2 (fp32 acc).
// ---------------------------------------------------------------------------
__global__ __launch_bounds__(256) void proj_mfma(
    const unsigned short* __restrict__ xb, const unsigned short* __restrict__ Wb,
    const float* __restrict__ a1, const float* __restrict__ a2,
    unsigned char* __restrict__ htq, float* __restrict__ f1,
    float* __restrict__ f2) {
  __shared__ __align__(16) unsigned short As[128 * 64];  // 16 KB
  __shared__ __align__(16) unsigned short Bs[64 * 64];   //  8 KB
  const int gid = blockIdx.x;
  const int b = gid & 7;                 // XCD-resident working set
  const int mt_ = (gid >> 3) & 7;
  const int ot_ = (gid >> 6) & 3;
  const int h = gid >> 8;
  const int hb = h * B_ + b;
  const int m0 = mt_ * 128, o0 = ot_ * 64;
  const int t = threadIdx.x, w = t >> 6, lane = t & 63;
  const int col = lane & 15, quad = lane >> 4;

  const int srow = t >> 3;
  const int sslot = t & 7;
  const int sseg = sslot ^ (srow & 7);
  const unsigned short* agp = xb + (size_t)(b * N_ + m0 + srow) * FIN + sseg * 8;
  const unsigned short* bgp = Wb + (size_t)(h * FOUT + o0 + srow) * FIN + sseg * 8;

  f32x4 acc[2][4];
  const f32x4 z4 = {0.f, 0.f, 0.f, 0.f};
#pragma unroll
  for (int mt = 0; mt < 2; ++mt)
#pragma unroll
    for (int ot = 0; ot < 4; ++ot) acc[mt][ot] = z4;

  s16x8 pa[4], pb[2];
#pragma unroll
  for (int i2 = 0; i2 < 4; ++i2) pa[i2] = *(const s16x8*)(agp + (size_t)i2 * 32 * FIN);
#pragma unroll
  for (int i2 = 0; i2 < 2; ++i2) pb[i2] = *(const s16x8*)(bgp + (size_t)i2 * 32 * FIN);

  for (int it = 0; it < FIN / 64; ++it) {
    __syncthreads();
#pragma unroll
    for (int i2 = 0; i2 < 4; ++i2)
      *(s16x8*)&As[(i2 * 32 + srow) * 64 + sslot * 8] = pa[i2];
#pragma unroll
    for (int i2 = 0; i2 < 2; ++i2)
      *(s16x8*)&Bs[(i2 * 32 + srow) * 64 + sslot * 8] = pb[i2];
    __syncthreads();
    if (it < FIN / 64 - 1) {
      const int k0 = (it + 1) * 64;
#pragma unroll
      for (int i2 = 0; i2 < 4; ++i2)
        pa[i2] = *(const s16x8*)(agp + (size_t)i2 * 32 * FIN + k0);
#pragma unroll
      for (int i2 = 0; i2 < 2; ++i2)
        pb[i2] = *(const s16x8*)(bgp + (size_t)i2 * 32 * FIN + k0);
    }
#pragma unroll
    for (int kb = 0; kb < 2; ++kb) {
      s16x8 af[2], bf[4];
#pragma unroll
      for (int mt = 0; mt < 2; ++mt) {
        const int row = w * 32 + mt * 16 + col;
        af[mt] = *(const s16x8*)&As[row * 64 + ((kb * 4 + quad) ^ (row & 7)) * 8];
      }
#pragma unroll
      for (int ot = 0; ot < 4; ++ot) {
        const int row = ot * 16 + col;
        bf[ot] = *(const s16x8*)&Bs[row * 64 + ((kb * 4 + quad) ^ (row & 7)) * 8];
      }
#pragma unroll
      for (int mt = 0; mt < 2; ++mt)
#pragma unroll
        for (int ot = 0; ot < 4; ++ot)
          acc[mt][ot] = __builtin_amdgcn_mfma_f32_16x16x32_bf16(af[mt], bf[ot],
                                                                acc[mt][ot], 0, 0, 0);
    }
  }

  // epilogue: fp8 transposed store + fused f1/f2 partials
  float pf1[2][4] = {{0.f}}, pf2[2][4] = {{0.f}};
#pragma unroll
  for (int mt = 0; mt < 2; ++mt) {
#pragma unroll
    for (int ot = 0; ot < 4; ++ot) {
      const int o = o0 + ot * 16 + col;
      const float va1 = a1[h * FOUT + o], va2 = a2[h * FOUT + o];
      const int m = m0 + w * 32 + mt * 16 + quad * 4;
      const unsigned int q =
          pk4_fp8(acc[mt][ot][0], acc[mt][ot][1], acc[mt][ot][2], acc[mt][ot][3]);
      *(unsigned int*)(htq + (size_t)(hb * FOUT + o) * N_ + m) = q;
#pragma unroll
      for (int r = 0; r < 4; ++r) {
        pf1[mt][r] += acc[mt][ot][r] * va1;
        pf2[mt][r] += acc[mt][ot][r] * va2;
      }
    }
  }
#pragma unroll
  for (int off = 1; off <= 8; off <<= 1)
#pragma unroll
    for (int mt = 0; mt < 2; ++mt)
#pragma unroll
      for (int r = 0; r < 4; ++r) {
        pf1[mt][r] += __shfl_xor(pf1[mt][r], off);
        pf2[mt][r] += __shfl_xor(pf2[mt][r], off);
      }
  if (col == 0) {
#pragma unroll
    for (int mt = 0; mt < 2; ++mt)
#pragma unroll
      for (int r = 0; r < 4; ++r) {
        const int n = m0 + w * 32 + mt * 16 + quad * 4 + r;
        atomicAdd(&f1[hb * N_ + n], pf1[mt][r]);
        atomicAdd(&f2[hb * N_ + n], pf2[mt][r]);
      }
  }
}

// ---------------------------------------------------------------------------
// Kernel 2: fused attention, 2 heads per block, fp8 weights + fp8 PV MFMA.
// Reduction-free score pass (analytic max bound + MFMA ones-column denom).
// launch_bounds(512,6): ~85-reg cap — NO SPILLS (R4/R5's (512,8) forced 32
// VGPRs -> 52 MB scratch traffic; that was the invariant 157us).
// wlds row stride 1044 B (odd dwords) -> PV A-reads ~2-way banks (free).
// ---------------------------------------------------------------------------
__global__ __launch_bounds__(512, 6) void attn_mfma(
    const unsigned char* __restrict__ htq, const float* __restrict__ f1,
    const float* __restrict__ f2, const int* __restrict__ adj,
    float* __restrict__ p0, float* __restrict__ p1, float* __restrict__ p2,
    float* __restrict__ p3) {
  __shared__ __align__(16) unsigned char wlds[32 * WROW];  // fp8 weights
  __shared__ unsigned int adjb[32][32];
  __shared__ float mred[2][8];

  const int id = blockIdx.x;
  const int b = id & 7;                 // XCD-keyed: htq[.][b] slices in L2
  const int g0 = (id >> 3) & 3;        // head group: heads {2g0, 2g0+1}
  const int i0 = (id >> 5) * 32;
  const int tid = threadIdx.x, w = tid >> 6, lane = tid & 63;
  const int col = lane & 15, quad = lane >> 4;

  // adjacency bitmask: 32 rows x 1024 bits, built once, reused for 2 heads
  for (int wi = tid; wi < 32 * 32; wi += 512) {
    const int row = wi >> 5, word = wi & 31;
    const int* ap = adj + (size_t)(b * N_ + i0 + row) * N_ + word * 32;
    unsigned int bits = 0;
#pragma unroll
    for (int k = 0; k < 32; k += 4) {
      int4 v = *(const int4*)(ap + k);
      bits |= (v.x ? 1u : 0u) << k;
      bits |= (v.y ? 1u : 0u) << (k + 1);
      bits |= (v.z ? 1u : 0u) << (k + 2);
      bits |= (v.w ? 1u : 0u) << (k + 3);
    }
    adjb[row][word] = bits;
  }

  // M2[s] = max_j f2[(2g0+s)*B+b][j]  (merged into the adjb barrier)
  float m2p[2];
#pragma unroll
  for (int s = 0; s < 2; ++s) {
    const float* fp = f2 + (size_t)((g0 * 2 + s) * B_ + b) * N_;
    m2p[s] = fmaxf(fp[tid], fp[tid + 512]);
#pragma unroll
    for (int off = 32; off; off >>= 1)
      m2p[s] = fmaxf(m2p[s], __shfl_xor(m2p[s], off));
  }
  if (lane == 0) { mred[0][w] = m2p[0]; mred[1][w] = m2p[1]; }
  __syncthreads();
  float M2[2];
#pragma unroll
  for (int s = 0; s < 2; ++s) {
    float m = mred[s][0];
#pragma unroll
    for (int k = 1; k < 8; ++k) m = fmaxf(m, mred[s][k]);
    M2[s] = m;
  }

  float hsum[2][2][4];
#pragma unroll
  for (int g = 0; g < 2; ++g)
#pragma unroll
    for (int t = 0; t < 2; ++t)
#pragma unroll
      for (int r = 0; r < 4; ++r) hsum[g][t][r] = 0.f;

  for (int hh = 0; hh < 2; ++hh) {
    const int h = g0 * 2 + hh;
    const int hb = h * B_ + b;
    const float* f1r = f1 + (size_t)hb * N_ + i0;
    // cache f2 row: lane owns j = c*256 + 4*lane .. +3
    float4 f2c[4];
#pragma unroll
    for (int c = 0; c < 4; ++c)
      f2c[c] = ((const float4*)(f2 + (size_t)hb * N_))[c * 64 + lane];

    // ---- scores: one pass, no reductions; wave w owns rows 4w..4w+3 ----
#pragma unroll
    for (int rr = 0; rr < 4; ++rr) {
      const int i = w * 4 + rr;
      const float f1i = f1r[i];
      const float tb = f1i + M2[hh];
      const float mhat = fmaxf(tb, ALPHA * tb);   // >= leaky(f1i+f2j) for all j
#pragma unroll
      for (int c = 0; c < 4; ++c) {
        const int j0 = c * 256 + (lane << 2);
        const unsigned int nib = (adjb[i][j0 >> 5] >> (j0 & 31)) & 0xFu;
        float ex[4];
#pragma unroll
        for (int k = 0; k < 4; ++k) {
          const float t = f1i + ((const float*)&f2c[c])[k];
          const float l = fmaxf(t, ALPHA * t);
          const float p = __expf(l - mhat);       // <= 1
          ex[k] = ((nib >> k) & 1u) ? p : 0.f;
        }
        *(unsigned int*)&wlds[i * WROW + c * 256 + (lane << 2)] =
            pk4_fp8(ex[0], ex[1], ex[2], ex[3]);
      }
    }
    __syncthreads();

    // ---- PV: fp8 MFMA; ones-column MFMA yields the softmax denominators ----
    f32x4 acc[2][2], accs[2];
    const f32x4 z4 = {0.f, 0.f, 0.f, 0.f};
#pragma unroll
    for (int g = 0; g < 2; ++g) {
      accs[g] = z4;
#pragma unroll
      for (int t = 0; t < 2; ++t) acc[g][t] = z4;
    }
    const long ones = 0x3838383838383838L;   // 8x fp8 e4m3 1.0

    const unsigned char* bp =
        htq + (size_t)(hb * FOUT + w * 32 + col) * N_ + quad * 8;
    const unsigned char* a0p = &wlds[col * WROW + quad * 8];
    const unsigned char* a1p = &wlds[(16 + col) * WROW + quad * 8];
#pragma unroll 4
    for (int kk = 0; kk < 32; ++kk) {
      // 4B-aligned pair loads (row stride 1044: odd i rows are 4 mod 8) ->
      // ds_read2_b32, ~2-way banks
      const unsigned int lo0 = *(const unsigned int*)(a0p + kk * 32);
      const unsigned int hi0 = *(const unsigned int*)(a0p + kk * 32 + 4);
      const unsigned int lo1 = *(const unsigned int*)(a1p + kk * 32);
      const unsigned int hi1 = *(const unsigned int*)(a1p + kk * 32 + 4);
      const long af0 = (long)(((unsigned long long)hi0 << 32) | lo0);
      const long af1 = (long)(((unsigned long long)hi1 << 32) | lo1);
      accs[0] = __builtin_amdgcn_mfma_f32_16x16x32_fp8_fp8(af0, ones, accs[0], 0, 0, 0);
      accs[1] = __builtin_amdgcn_mfma_f32_16x16x32_fp8_fp8(af1, ones, accs[1], 0, 0, 0);
#pragma unroll
      for (int t = 0; t < 2; ++t) {
        const long bf = *(const long*)(bp + (size_t)t * 16 * N_ + kk * 32);
        acc[0][t] = __builtin_amdgcn_mfma_f32_16x16x32_fp8_fp8(af0, bf,
                                                               acc[0][t], 0, 0, 0);
        acc[1][t] = __builtin_amdgcn_mfma_f32_16x16x32_fp8_fp8(af1, bf,
                                                               acc[1][t], 0, 0, 0);
      }
    }

    // normalize (denominator = accs, same quantized weights as numerator),
    // ELU, head-sum
#pragma unroll
    for (int g = 0; g < 2; ++g)
#pragma unroll
      for (int r = 0; r < 4; ++r) {
        const float inv = 1.0f / accs[g][r];
#pragma unroll
        for (int t = 0; t < 2; ++t) {
          const float oh = acc[g][t][r] * inv;
          hsum[g][t][r] += oh > 0.f ? oh : __expf(oh) - 1.f;
        }
      }
    __syncthreads();   // wlds reused next head
  }

  // ---- write head-group partial ----
  float* pdst = (g0 == 0) ? p0 : (g0 == 1) ? p1 : (g0 == 2) ? p2 : p3;
#pragma unroll
  for (int g = 0; g < 2; ++g)
#pragma unroll
    for (int t = 0; t < 2; ++t)
#pragma unroll
      for (int r = 0; r < 4; ++r) {
        const int row = g * 16 + quad * 4 + r;
        pdst[(size_t)(b * N_ + i0 + row) * FOUT + w * 32 + t * 16 + col] =
            hsum[g][t][r];
      }
}

// ---------------------------------------------------------------------------
// Kernel 3: sum 4 head-group partials + log_softmax over o. Wave per row.
// ---------------------------------------------------------------------------
__global__ __launch_bounds__(256) void logsm(
    const float* __restrict__ p0, const float* __restrict__ p1,
    const float* __restrict__ p2, const float* __restrict__ p3,
    float* __restrict__ out) {
  const int row = blockIdx.x * 4 + (threadIdx.x >> 6);
  const int lane = threadIdx.x & 63;
  const size_t base = (size_t)row * FOUT;
  float v[4];
  float m = -3.0e38f;
#pragma unroll
  for (int c = 0; c < 4; ++c) {
    const size_t idx = base + c * 64 + lane;
    v[c] = p0[idx] + p1[idx] + p2[idx] + p3[idx];
    m = fmaxf(m, v[c]);
  }
#pragma unroll
  for (int off = 32; off; off >>= 1) m = fmaxf(m, __shfl_xor(m, off));
  float s = 0.f;
#pragma unroll
  for (int c = 0; c < 4; ++c) s += __expf(v[c] - m);
#pragma unroll
  for (int off = 32; off; off >>= 1) s += __shfl_xor(s, off);
  const float lg = m + logf(s);
#pragma unroll
  for (int c = 0; c < 4; ++c)
    out[base + c * 64 + lane] = v[c] - lg;
}

// ---------------------------------------------------------------------------
extern "C" void kernel_launch(void* const* d_in, const int* in_sizes, int n_in,
                              void* d_out, int out_size, void* d_ws,
                              size_t ws_size, hipStream_t stream) {
  const float* x   = (const float*)d_in[0];
  const int*   adj = (const int*)d_in[1];
  const float* W   = (const float*)d_in[2];
  const float* a1  = (const float*)d_in[3];
  const float* a2  = (const float*)d_in[4];
  float* out = (float*)d_out;

  unsigned char* htq = (unsigned char*)d_ws;                          // 16 MB fp8 h^T
  unsigned short* xb = (unsigned short*)(htq + (size_t)H_ * B_ * FOUT * N_); // 8 MB
  unsigned short* Wb = xb + (size_t)XT;                               // 2 MB
  float* f1 = (float*)(Wb + (size_t)WT);                              // 256 KB
  float* f2 = f1 + (size_t)H_ * B_ * N_;                              // 256 KB
  float* part2 = f2 + (size_t)H_ * B_ * N_;                           // 8 MB
  float* part3 = part2 + (size_t)B_ * N_ * FOUT;                      // 8 MB
  float* part1 = (float*)xb;   // xb dead after proj_mfma (8 MB reuse)

  convert_bf16<<<(XT + WT) / 1024 + 128, 256, 0, stream>>>(x, W, xb, Wb, f1);

  proj_mfma<<<2048, 256, 0, stream>>>(xb, Wb, a1, a2, htq, f1, f2);

  attn_mfma<<<1024, 512, 0, stream>>>(htq, f1, f2, adj, out, part1, part2, part3);

  logsm<<<(B_ * N_) / 4, 256, 0, stream>>>(out, part1, part2, part3, out);
}